// Round 1
// baseline (866.291 us; speedup 1.0000x reference)
//
#include <hip/hip_runtime.h>
#include <hip/hip_bf16.h>
#include <math.h>

#define BB 4
#define KK 2048
#define DD 256
#define HH 8
#define HD 32
#define HALF 128
#define QUARTER 64

// ---------------------------------------------------------------------------
// Kernel 1: 2D RoPE. One thread per (row, pair). xr[b,k,:] = rotated x[b,k,:].
// x_part = x[:, :128] rotated by rope_cache[x_pos] (coords[...,1]);
// y_part = x[:, 128:] rotated by rope_cache[y_pos] (coords[...,0]).
// ---------------------------------------------------------------------------
__global__ __launch_bounds__(256) void rope_kernel(
    const float* __restrict__ x, const int* __restrict__ coords,
    const float* __restrict__ rope_cache, const int* __restrict__ image_size_p,
    int max_pos, float* __restrict__ xr)
{
    int idx = blockIdx.x * blockDim.x + threadIdx.x;
    if (idx >= BB * KK * HALF) return;
    int p   = idx % HALF;   // pair index within row (0..127)
    int row = idx / HALF;   // b*K + k

    float img = (float)image_size_p[0];
    float mp1 = (float)(max_pos - 1);
    int c0 = coords[row * 2 + 0];  // y coordinate
    int c1 = coords[row * 2 + 1];  // x coordinate
    // replicate jnp: clip(c/image_size * (max_pos-1), 0, max_pos-1) then int cast
    float cy = fminf(fmaxf(((float)c0 / img) * mp1, 0.0f), mp1);
    float cx = fminf(fmaxf(((float)c1 / img) * mp1, 0.0f), mp1);
    int y_pos = (int)cy;
    int x_pos = (int)cx;

    int j, pos, base;
    if (p < QUARTER) { j = p;           pos = x_pos; base = 2 * j; }        // first half
    else             { j = p - QUARTER; pos = y_pos; base = HALF + 2 * j; } // second half

    const float* rc = rope_cache + ((size_t)pos * QUARTER + j) * 2;
    float c = rc[0], s = rc[1];
    const float* xin = x + (size_t)row * DD + base;
    float p0 = xin[0], p1 = xin[1];
    float* xo = xr + (size_t)row * DD + base;
    xo[0] = p0 * c - p1 * s;
    xo[1] = p0 * s + p1 * c;
}

// ---------------------------------------------------------------------------
// Kernel 2/4: fp32 GEMM, A[M,256] @ W[256,256] + bias.
// blockIdx.z selects which of up to 3 weight/bias/out sets (for fused qkv).
// head_layout=1: write out[((b*H+h)*K + tok)*32 + d]; else row-major [M,256].
// 64x64 tile, 256 threads, 4x4 microtile, K staged 64 at a time in LDS.
// ---------------------------------------------------------------------------
__global__ __launch_bounds__(256) void gemm_kernel(
    const float* __restrict__ A,
    const float* __restrict__ W0, const float* __restrict__ W1, const float* __restrict__ W2,
    const float* __restrict__ b0, const float* __restrict__ b1, const float* __restrict__ b2,
    float* __restrict__ o0, float* __restrict__ o1, float* __restrict__ o2,
    int head_layout)
{
    const float* Wp = (blockIdx.z == 0) ? W0 : (blockIdx.z == 1) ? W1 : W2;
    const float* bp = (blockIdx.z == 0) ? b0 : (blockIdx.z == 1) ? b1 : b2;
    float*       op = (blockIdx.z == 0) ? o0 : (blockIdx.z == 1) ? o1 : o2;

    int m0 = blockIdx.x * 64;
    int n0 = blockIdx.y * 64;
    int tid = threadIdx.x;
    int ty = tid / 16, tx = tid % 16;

    __shared__ float As[64][65];
    __shared__ float Bs[64][65];

    float acc[4][4] = {};

    for (int k0 = 0; k0 < DD; k0 += 64) {
        __syncthreads();
        #pragma unroll
        for (int l = 0; l < 4; ++l) {
            int f  = tid + l * 256;          // 0..1023 float4 slots
            int mr = f / 16;
            int k4 = (f % 16) * 4;
            float4 av = *(const float4*)(A  + (size_t)(m0 + mr) * DD + k0 + k4);
            As[mr][k4 + 0] = av.x; As[mr][k4 + 1] = av.y;
            As[mr][k4 + 2] = av.z; As[mr][k4 + 3] = av.w;
            float4 wv = *(const float4*)(Wp + (size_t)(k0 + mr) * DD + n0 + k4);
            Bs[mr][k4 + 0] = wv.x; Bs[mr][k4 + 1] = wv.y;
            Bs[mr][k4 + 2] = wv.z; Bs[mr][k4 + 3] = wv.w;
        }
        __syncthreads();
        #pragma unroll 8
        for (int kk = 0; kk < 64; ++kk) {
            float a[4], b[4];
            #pragma unroll
            for (int i = 0; i < 4; ++i) a[i] = As[ty + 16 * i][kk];
            #pragma unroll
            for (int j = 0; j < 4; ++j) b[j] = Bs[kk][tx + 16 * j];
            #pragma unroll
            for (int i = 0; i < 4; ++i)
                #pragma unroll
                for (int j = 0; j < 4; ++j)
                    acc[i][j] += a[i] * b[j];
        }
    }

    #pragma unroll
    for (int i = 0; i < 4; ++i) {
        int gm = m0 + ty + 16 * i;
        #pragma unroll
        for (int j = 0; j < 4; ++j) {
            int gn = n0 + tx + 16 * j;
            float val = acc[i][j] + bp[gn];
            if (head_layout) {
                int b   = gm >> 11;        // / 2048
                int tok = gm & 2047;
                int h   = gn >> 5;         // / 32
                int d   = gn & 31;
                op[(((size_t)b * HH + h) * KK + tok) * HD + d] = val;
            } else {
                op[(size_t)gm * DD + gn] = val;
            }
        }
    }
}

// ---------------------------------------------------------------------------
// Kernel 3: masked flash attention, fp32.
// Grid (K/64, H, B), 64 threads (1 wave). Thread t owns q-row qb*64+t.
// K/V tiles of 32 keys staged in LDS; broadcast reads for dot products.
// allowed(q,k) = !ctx_q || ctx_k. Online softmax, two-pass per tile.
// ---------------------------------------------------------------------------
__global__ __launch_bounds__(64) void attn_kernel(
    const float* __restrict__ q, const float* __restrict__ k,
    const float* __restrict__ v, const int* __restrict__ is_ctx,
    float* __restrict__ out)
{
    const int b  = blockIdx.z;
    const int h  = blockIdx.y;
    const int qb = blockIdx.x;
    const int t  = threadIdx.x;
    const int qi = qb * 64 + t;

    const float scale = 0.17677669529663687f;  // 32^-0.5

    const float* qrow = q + (((size_t)b * HH + h) * KK + qi) * HD;
    float qv[HD];
    #pragma unroll
    for (int d = 0; d < HD; d += 4) {
        float4 f = *(const float4*)(qrow + d);
        qv[d] = f.x; qv[d + 1] = f.y; qv[d + 2] = f.z; qv[d + 3] = f.w;
    }
    const bool qctx = is_ctx[(size_t)b * KK + qi] != 0;

    float m = -INFINITY, l = 0.0f;
    float acc[HD];
    #pragma unroll
    for (int d = 0; d < HD; ++d) acc[d] = 0.0f;

    __shared__ float Ks[32][HD];
    __shared__ float Vs[32][HD];
    __shared__ int   cs[32];

    const float* kbase = k + ((size_t)b * HH + h) * KK * HD;
    const float* vbase = v + ((size_t)b * HH + h) * KK * HD;

    for (int kt = 0; kt < KK; kt += 32) {
        __syncthreads();
        #pragma unroll
        for (int l4 = 0; l4 < 4; ++l4) {
            int f  = t + l4 * 64;        // 0..255 float4 slots
            int kj = f / 8;
            int d4 = (f % 8) * 4;
            *(float4*)&Ks[kj][d4] = *(const float4*)(kbase + (size_t)(kt + kj) * HD + d4);
            *(float4*)&Vs[kj][d4] = *(const float4*)(vbase + (size_t)(kt + kj) * HD + d4);
        }
        if (t < 32) cs[t] = is_ctx[(size_t)b * KK + kt + t];
        __syncthreads();

        float s[32];
        float tmax = -INFINITY;
        #pragma unroll
        for (int j = 0; j < 32; ++j) {
            float dot = 0.0f;
            #pragma unroll
            for (int d = 0; d < HD; ++d) dot += qv[d] * Ks[j][d];
            bool ok = (!qctx) || (cs[j] != 0);
            s[j] = ok ? dot * scale : -INFINITY;
            tmax = fmaxf(tmax, s[j]);
        }

        float mnew = fmaxf(m, tmax);
        if (mnew != -INFINITY) {           // guard: all-masked-so-far tiles
            float corr = __expf(m - mnew); // m=-inf -> 0, correct
            l *= corr;
            #pragma unroll
            for (int d = 0; d < HD; ++d) acc[d] *= corr;
            #pragma unroll
            for (int j = 0; j < 32; ++j) {
                float p = __expf(s[j] - mnew);  // s=-inf -> 0
                l += p;
                #pragma unroll
                for (int d = 0; d < HD; ++d) acc[d] += p * Vs[j][d];
            }
            m = mnew;
        }
    }

    float inv = 1.0f / l;   // every row has >=1 allowed key (self if context)
    float* orow = out + ((size_t)b * KK + qi) * DD + h * HD;
    #pragma unroll
    for (int d = 0; d < HD; ++d) orow[d] = acc[d] * inv;
}

// ---------------------------------------------------------------------------
extern "C" void kernel_launch(void* const* d_in, const int* in_sizes, int n_in,
                              void* d_out, int out_size, void* d_ws, size_t ws_size,
                              hipStream_t stream)
{
    const float* x        = (const float*)d_in[0];
    const int*   coords   = (const int*)  d_in[1];
    const int*   is_ctx   = (const int*)  d_in[2];
    const int*   img_sz   = (const int*)  d_in[3];
    const float* Wq       = (const float*)d_in[4];
    const float* bq       = (const float*)d_in[5];
    const float* Wk       = (const float*)d_in[6];
    const float* bk       = (const float*)d_in[7];
    const float* Wv       = (const float*)d_in[8];
    const float* bv       = (const float*)d_in[9];
    const float* Wo       = (const float*)d_in[10];
    const float* bo       = (const float*)d_in[11];
    const float* rope     = (const float*)d_in[12];

    int max_pos = in_sizes[12] / (QUARTER * 2);   // 224

    const size_t NTOK = (size_t)BB * KK;          // 8192
    const size_t NELT = NTOK * DD;                // 2,097,152 floats per tensor

    float* ws   = (float*)d_ws;
    float* xr   = ws;
    float* qb_  = xr  + NELT;
    float* kb_  = qb_ + NELT;
    float* vb_  = kb_ + NELT;
    float* ao   = vb_ + NELT;
    float* outp = (float*)d_out;

    // 1) RoPE
    {
        int total = BB * KK * HALF;
        rope_kernel<<<(total + 255) / 256, 256, 0, stream>>>(
            x, coords, rope, img_sz, max_pos, xr);
    }
    // 2) QKV projections (fused over blockIdx.z), head-layout outputs
    gemm_kernel<<<dim3(NTOK / 64, DD / 64, 3), 256, 0, stream>>>(
        xr, Wq, Wk, Wv, bq, bk, bv, qb_, kb_, vb_, 1);
    // 3) Attention
    attn_kernel<<<dim3(KK / 64, HH, BB), 64, 0, stream>>>(
        qb_, kb_, vb_, is_ctx, ao);
    // 4) Output projection -> d_out
    gemm_kernel<<<dim3(NTOK / 64, DD / 64, 1), 256, 0, stream>>>(
        ao, Wo, Wo, Wo, bo, bo, bo, outp, outp, outp, 0);
}

// Round 2
// 290.555 us; speedup vs baseline: 2.9815x; 2.9815x over previous
//
#include <hip/hip_runtime.h>
#include <math.h>

#define BB 4
#define KK 2048
#define DD 256
#define HH 8
#define HD 32
#define HALF 128
#define QUARTER 64

typedef __attribute__((ext_vector_type(8))) short bf16x8;
typedef __attribute__((ext_vector_type(4))) float f32x4;

__device__ __forceinline__ ushort f2bf(float f) {
    unsigned u = __builtin_bit_cast(unsigned, f);
    u += 0x7fffu + ((u >> 16) & 1u);   // RNE
    return (ushort)(u >> 16);
}

// ---------------------------------------------------------------------------
// Kernel 1: 2D RoPE (fp32), unchanged from round 0.
// ---------------------------------------------------------------------------
__global__ __launch_bounds__(256) void rope_kernel(
    const float* __restrict__ x, const int* __restrict__ coords,
    const float* __restrict__ rope_cache, const int* __restrict__ image_size_p,
    int max_pos, float* __restrict__ xr)
{
    int idx = blockIdx.x * blockDim.x + threadIdx.x;
    if (idx >= BB * KK * HALF) return;
    int p   = idx % HALF;
    int row = idx / HALF;

    float img = (float)image_size_p[0];
    float mp1 = (float)(max_pos - 1);
    int c0 = coords[row * 2 + 0];
    int c1 = coords[row * 2 + 1];
    float cy = fminf(fmaxf(((float)c0 / img) * mp1, 0.0f), mp1);
    float cx = fminf(fmaxf(((float)c1 / img) * mp1, 0.0f), mp1);
    int y_pos = (int)cy;
    int x_pos = (int)cx;

    int j, pos, base;
    if (p < QUARTER) { j = p;           pos = x_pos; base = 2 * j; }
    else             { j = p - QUARTER; pos = y_pos; base = HALF + 2 * j; }

    const float* rc = rope_cache + ((size_t)pos * QUARTER + j) * 2;
    float c = rc[0], s = rc[1];
    const float* xin = x + (size_t)row * DD + base;
    float p0 = xin[0], p1 = xin[1];
    float* xo = xr + (size_t)row * DD + base;
    xo[0] = p0 * c - p1 * s;
    xo[1] = p0 * s + p1 * c;
}

// ---------------------------------------------------------------------------
// Kernel 2/4: fp32 GEMM, A[M,256] @ W[256,256] + bias, epilogue modes:
//   fused_qkv=1: z=0/1 -> bf16 [B,H,K,32] (q,k); z=2 -> bf16 V^T [B,H,32,K]
//   fused_qkv=0: fp32 row-major [M,256] (output projection)
// bf16 modes stage the 64x64 tile through LDS for coalesced 16B stores.
// ---------------------------------------------------------------------------
__global__ __launch_bounds__(256) void gemm_kernel(
    const float* __restrict__ A,
    const float* __restrict__ W0, const float* __restrict__ W1, const float* __restrict__ W2,
    const float* __restrict__ b0, const float* __restrict__ b1, const float* __restrict__ b2,
    void* __restrict__ o0, void* __restrict__ o1, void* __restrict__ o2,
    int fused_qkv)
{
    const float* Wp = (blockIdx.z == 0) ? W0 : (blockIdx.z == 1) ? W1 : W2;
    const float* bp = (blockIdx.z == 0) ? b0 : (blockIdx.z == 1) ? b1 : b2;
    void*        op = (blockIdx.z == 0) ? o0 : (blockIdx.z == 1) ? o1 : o2;
    const int mode = fused_qkv ? ((blockIdx.z == 2) ? 2 : 1) : 0;

    int m0 = blockIdx.x * 64;
    int n0 = blockIdx.y * 64;
    int tid = threadIdx.x;
    int ty = tid / 16, tx = tid % 16;

    __shared__ float As[64][65];
    __shared__ float Bs[64][65];
    __shared__ ushort tbuf[64][72];

    float acc[4][4] = {};

    for (int k0 = 0; k0 < DD; k0 += 64) {
        __syncthreads();
        #pragma unroll
        for (int l = 0; l < 4; ++l) {
            int f  = tid + l * 256;
            int mr = f / 16;
            int k4 = (f % 16) * 4;
            float4 av = *(const float4*)(A  + (size_t)(m0 + mr) * DD + k0 + k4);
            As[mr][k4 + 0] = av.x; As[mr][k4 + 1] = av.y;
            As[mr][k4 + 2] = av.z; As[mr][k4 + 3] = av.w;
            float4 wv = *(const float4*)(Wp + (size_t)(k0 + mr) * DD + n0 + k4);
            Bs[mr][k4 + 0] = wv.x; Bs[mr][k4 + 1] = wv.y;
            Bs[mr][k4 + 2] = wv.z; Bs[mr][k4 + 3] = wv.w;
        }
        __syncthreads();
        #pragma unroll 8
        for (int kk = 0; kk < 64; ++kk) {
            float a[4], b[4];
            #pragma unroll
            for (int i = 0; i < 4; ++i) a[i] = As[ty + 16 * i][kk];
            #pragma unroll
            for (int j = 0; j < 4; ++j) b[j] = Bs[kk][tx + 16 * j];
            #pragma unroll
            for (int i = 0; i < 4; ++i)
                #pragma unroll
                for (int j = 0; j < 4; ++j)
                    acc[i][j] += a[i] * b[j];
        }
    }

    if (mode == 0) {
        float* opf = (float*)op;
        #pragma unroll
        for (int i = 0; i < 4; ++i) {
            int gm = m0 + ty + 16 * i;
            #pragma unroll
            for (int j = 0; j < 4; ++j) {
                int gn = n0 + tx + 16 * j;
                opf[(size_t)gm * DD + gn] = acc[i][j] + bp[gn];
            }
        }
        return;
    }

    // bf16 modes: stage through LDS (mode1: [tok][d]; mode2: [d][tok])
    __syncthreads();
    #pragma unroll
    for (int i = 0; i < 4; ++i) {
        #pragma unroll
        for (int j = 0; j < 4; ++j) {
            ushort h = f2bf(acc[i][j] + bp[n0 + tx + 16 * j]);
            if (mode == 1) tbuf[ty + 16 * i][tx + 16 * j] = h;
            else           tbuf[tx + 16 * j][ty + 16 * i] = h;
        }
    }
    __syncthreads();
    ushort* oph = (ushort*)op;
    #pragma unroll
    for (int s2 = 0; s2 < 2; ++s2) {
        int slot = tid + s2 * 256;        // 0..511
        int rrow = slot >> 3;
        int seg  = slot & 7;
        uint4 d4 = *(const uint4*)&tbuf[rrow][seg * 8];
        if (mode == 1) {
            int gm = m0 + rrow; int bI = gm >> 11, tok = gm & 2047;
            int d0 = n0 + seg * 8; int hI = d0 >> 5, dI = d0 & 31;
            *(uint4*)(oph + (((size_t)bI * HH + hI) * KK + tok) * HD + dI) = d4;
        } else {
            int d0 = n0 + rrow; int hI = d0 >> 5, dI = d0 & 31;
            int bI = m0 >> 11; int tok = (m0 & 2047) + seg * 8;
            *(uint4*)(oph + (((size_t)bI * HH + hI) * HD + dI) * KK + tok) = d4;
        }
    }
}

// ---------------------------------------------------------------------------
// Kernel 3: masked flash attention, bf16 MFMA (16x16x32, K=hd=32).
// Grid (K/128, H, B), 256 threads = 4 waves; wave owns 32 q rows.
// S layout: row=q=(l>>4)*4+r, col=key=l&15 -> softmax reduce = shfl_xor over
// 16 lanes; m/l land in O-row distribution (no redistribution).
// P round-trips LDS with XOR swizzle (byte ^= (row&7)<<4) for conflict-free
// ds_read_b128 PV fragments. V is pre-transposed [B,H,32,K].
// ---------------------------------------------------------------------------
__global__ __launch_bounds__(256) void attn_mfma_kernel(
    const ushort* __restrict__ qb, const ushort* __restrict__ kb,
    const ushort* __restrict__ vt, const int* __restrict__ is_ctx,
    float* __restrict__ out)
{
    const int b  = blockIdx.z;
    const int h  = blockIdx.y;
    const int bh = b * HH + h;
    const int tid = threadIdx.x;
    const int w  = tid >> 6;
    const int l  = tid & 63;
    const int lg = l >> 4;      // lane group 0..3
    const int ll = l & 15;
    const int q0 = blockIdx.x * 128 + w * 32;

    const float SCALE = 0.17677669529663687f;   // 32^-0.5

    __shared__ ushort Pl[4][32][64];
    char* Pw = (char*)&Pl[w][0][0];

    // Q fragments (A operand): lane = q row (ll), dims lg*8..+7
    const ushort* qbase = qb + ((size_t)bh * KK + q0) * HD;
    bf16x8 qf[2];
    qf[0] = *(const bf16x8*)(qbase + (size_t)ll * HD + lg * 8);
    qf[1] = *(const bf16x8*)(qbase + (size_t)(16 + ll) * HD + lg * 8);

    bool qc[2][4];
    #pragma unroll
    for (int qt = 0; qt < 2; ++qt)
        #pragma unroll
        for (int r = 0; r < 4; ++r)
            qc[qt][r] = is_ctx[b * KK + q0 + qt * 16 + lg * 4 + r] != 0;

    float m[2][4], ls[2][4];
    f32x4 acc[2][2];
    #pragma unroll
    for (int qt = 0; qt < 2; ++qt) {
        #pragma unroll
        for (int r = 0; r < 4; ++r) { m[qt][r] = -INFINITY; ls[qt][r] = 0.0f; }
        #pragma unroll
        for (int dt = 0; dt < 2; ++dt) acc[qt][dt] = (f32x4){0.f, 0.f, 0.f, 0.f};
    }

    const ushort* kbase = kb + (size_t)bh * KK * HD;
    const ushort* vbase = vt + (size_t)bh * HD * KK;
    const int* cbase = is_ctx + (size_t)b * KK;
    const f32x4 zero = {0.f, 0.f, 0.f, 0.f};

    for (int kt0 = 0; kt0 < KK; kt0 += 64) {
        // K fragments (B operand): lane = key (ll), dims lg*8..+7
        bf16x8 kf[4];
        int kc[4];
        #pragma unroll
        for (int kt = 0; kt < 4; ++kt) {
            kf[kt] = *(const bf16x8*)(kbase + (size_t)(kt0 + kt * 16 + ll) * HD + lg * 8);
            kc[kt] = cbase[kt0 + kt * 16 + ll];
        }

        // S = Q K^T
        f32x4 s[2][4];
        #pragma unroll
        for (int qt = 0; qt < 2; ++qt)
            #pragma unroll
            for (int kt = 0; kt < 4; ++kt)
                s[qt][kt] = __builtin_amdgcn_mfma_f32_16x16x32_bf16(qf[qt], kf[kt], zero, 0, 0, 0);

        // masked online softmax; write P (bf16) to swizzled LDS
        #pragma unroll
        for (int qt = 0; qt < 2; ++qt) {
            #pragma unroll
            for (int r = 0; r < 4; ++r) {
                float tm = -INFINITY;
                #pragma unroll
                for (int kt = 0; kt < 4; ++kt) {
                    float sv = s[qt][kt][r] * SCALE;
                    sv = (!qc[qt][r] || kc[kt]) ? sv : -INFINITY;
                    s[qt][kt][r] = sv;
                    tm = fmaxf(tm, sv);
                }
                tm = fmaxf(tm, __shfl_xor(tm, 1));
                tm = fmaxf(tm, __shfl_xor(tm, 2));
                tm = fmaxf(tm, __shfl_xor(tm, 4));
                tm = fmaxf(tm, __shfl_xor(tm, 8));
                float mnew  = fmaxf(m[qt][r], tm);
                float msafe = fmaxf(mnew, -1e37f);   // all-masked guard
                float corr  = __expf(m[qt][r] - msafe);
                m[qt][r] = mnew;
                ls[qt][r] *= corr;
                acc[qt][0][r] *= corr;
                acc[qt][1][r] *= corr;
                float psum = 0.0f;
                int qrow = qt * 16 + lg * 4 + r;
                #pragma unroll
                for (int kt = 0; kt < 4; ++kt) {
                    float p = __expf(s[qt][kt][r] - msafe);
                    psum += p;
                    int kcol = kt * 16 + ll;
                    *(ushort*)(Pw + qrow * 128 + ((kcol * 2) ^ ((qrow & 7) << 4))) = f2bf(p);
                }
                psum += __shfl_xor(psum, 1);
                psum += __shfl_xor(psum, 2);
                psum += __shfl_xor(psum, 4);
                psum += __shfl_xor(psum, 8);
                ls[qt][r] += psum;
            }
        }

        // O += P V  (A = P from LDS, B = V^T rows -> contiguous)
        #pragma unroll
        for (int ks = 0; ks < 2; ++ks) {
            bf16x8 pf[2];
            #pragma unroll
            for (int qt = 0; qt < 2; ++qt) {
                int qrow = qt * 16 + ll;
                pf[qt] = *(const bf16x8*)(Pw + qrow * 128 + ((ks * 64 + lg * 16) ^ ((qrow & 7) << 4)));
            }
            #pragma unroll
            for (int dt = 0; dt < 2; ++dt) {
                bf16x8 vf = *(const bf16x8*)(vbase + (size_t)(dt * 16 + ll) * KK + kt0 + ks * 32 + lg * 8);
                acc[0][dt] = __builtin_amdgcn_mfma_f32_16x16x32_bf16(pf[0], vf, acc[0][dt], 0, 0, 0);
                acc[1][dt] = __builtin_amdgcn_mfma_f32_16x16x32_bf16(pf[1], vf, acc[1][dt], 0, 0, 0);
            }
        }
    }

    // epilogue: divide by l, write fp32 [B,K,256]
    #pragma unroll
    for (int qt = 0; qt < 2; ++qt) {
        #pragma unroll
        for (int r = 0; r < 4; ++r) {
            float inv = 1.0f / ls[qt][r];
            int q = q0 + qt * 16 + lg * 4 + r;
            #pragma unroll
            for (int dt = 0; dt < 2; ++dt)
                out[((size_t)b * KK + q) * DD + h * HD + dt * 16 + ll] = acc[qt][dt][r] * inv;
        }
    }
}

// ---------------------------------------------------------------------------
extern "C" void kernel_launch(void* const* d_in, const int* in_sizes, int n_in,
                              void* d_out, int out_size, void* d_ws, size_t ws_size,
                              hipStream_t stream)
{
    const float* x        = (const float*)d_in[0];
    const int*   coords   = (const int*)  d_in[1];
    const int*   is_ctx   = (const int*)  d_in[2];
    const int*   img_sz   = (const int*)  d_in[3];
    const float* Wq       = (const float*)d_in[4];
    const float* bq       = (const float*)d_in[5];
    const float* Wk       = (const float*)d_in[6];
    const float* bk       = (const float*)d_in[7];
    const float* Wv       = (const float*)d_in[8];
    const float* bv       = (const float*)d_in[9];
    const float* Wo       = (const float*)d_in[10];
    const float* bo       = (const float*)d_in[11];
    const float* rope     = (const float*)d_in[12];

    int max_pos = in_sizes[12] / (QUARTER * 2);   // 224

    const size_t NTOK = (size_t)BB * KK;          // 8192
    const size_t NELT = NTOK * DD;                // 2,097,152

    char* ws = (char*)d_ws;
    float*  xr   = (float*) (ws);                          // 8 MB
    float*  ao   = (float*) (ws + NELT * 4);               // 8 MB
    ushort* qbf  = (ushort*)(ws + NELT * 8);               // 4 MB
    ushort* kbf  = (ushort*)(ws + NELT * 8 + NELT * 2);    // 4 MB
    ushort* vtbf = (ushort*)(ws + NELT * 8 + NELT * 4);    // 4 MB
    float* outp = (float*)d_out;

    // 1) RoPE
    {
        int total = BB * KK * HALF;
        rope_kernel<<<(total + 255) / 256, 256, 0, stream>>>(
            x, coords, rope, img_sz, max_pos, xr);
    }
    // 2) QKV projections -> bf16 q/k [B,H,K,32], V^T [B,H,32,K]
    gemm_kernel<<<dim3(NTOK / 64, DD / 64, 3), 256, 0, stream>>>(
        xr, Wq, Wk, Wv, bq, bk, bv, qbf, kbf, vtbf, 1);
    // 3) MFMA flash attention -> ao fp32 [B,K,256]
    attn_mfma_kernel<<<dim3(KK / 128, HH, BB), 256, 0, stream>>>(
        qbf, kbf, vtbf, is_ctx, ao);
    // 4) Output projection -> d_out (fp32)
    gemm_kernel<<<dim3(NTOK / 64, DD / 64, 1), 256, 0, stream>>>(
        ao, Wo, Wo, Wo, bo, bo, bo, outp, outp, outp, 0);
}

// Round 3
// 220.913 us; speedup vs baseline: 3.9214x; 1.3152x over previous
//
#include <hip/hip_runtime.h>
#include <hip/hip_bf16.h>
#include <math.h>

#define BB 4
#define KK 2048
#define DD 256
#define HH 8
#define HD 32
#define HALF 128
#define QUARTER 64

typedef __attribute__((ext_vector_type(8))) short bf16x8;
typedef __attribute__((ext_vector_type(4))) float f32x4;

// 1/sqrt(32) * log2(e): scores produced directly in log2 domain
#define SCALE2F (0.17677669529663687f * 1.4426950408889634f)
#define MASKNEG -3.0e38f

__device__ __forceinline__ ushort f2bf(float f) {       // RNE, for epilogues
    unsigned u = __builtin_bit_cast(unsigned, f);
    u += 0x7fffu + ((u >> 16) & 1u);
    return (ushort)(u >> 16);
}
__device__ __forceinline__ unsigned pkbf(float a, float b) {  // HW cvt path
    ushort ua = __builtin_bit_cast(ushort, __float2bfloat16(a));
    ushort ub = __builtin_bit_cast(ushort, __float2bfloat16(b));
    return (unsigned)ua | ((unsigned)ub << 16);
}

// ---------------------------------------------------------------------------
// Kernel 1: 2D RoPE fp32->bf16, plus per-(b,key) mask bias array
// maskbias[b*K+k] = is_ctx ? 0 : -3e38 (added to scores of ctx q-rows).
// ---------------------------------------------------------------------------
__global__ __launch_bounds__(256) void rope_kernel(
    const float* __restrict__ x, const int* __restrict__ coords,
    const float* __restrict__ rope_cache, const int* __restrict__ image_size_p,
    const int* __restrict__ is_ctx, int max_pos,
    ushort* __restrict__ xr16, float* __restrict__ mbias)
{
    int idx = blockIdx.x * blockDim.x + threadIdx.x;
    if (idx >= BB * KK * HALF) return;
    int p   = idx % HALF;
    int row = idx / HALF;

    float img = (float)image_size_p[0];
    float mp1 = (float)(max_pos - 1);
    int c0 = coords[row * 2 + 0];
    int c1 = coords[row * 2 + 1];
    float cy = fminf(fmaxf(((float)c0 / img) * mp1, 0.0f), mp1);
    float cx = fminf(fmaxf(((float)c1 / img) * mp1, 0.0f), mp1);
    int y_pos = (int)cy;
    int x_pos = (int)cx;

    int j, pos, base;
    if (p < QUARTER) { j = p;           pos = x_pos; base = 2 * j; }
    else             { j = p - QUARTER; pos = y_pos; base = HALF + 2 * j; }

    const float* rc = rope_cache + ((size_t)pos * QUARTER + j) * 2;
    float c = rc[0], s = rc[1];
    const float* xin = x + (size_t)row * DD + base;
    float p0 = xin[0], p1 = xin[1];
    unsigned u = (unsigned)f2bf(p0 * c - p1 * s) |
                 ((unsigned)f2bf(p0 * s + p1 * c) << 16);
    *(unsigned*)(xr16 + (size_t)row * DD + base) = u;

    if (p == 0) mbias[row] = (is_ctx[row] != 0) ? 0.0f : MASKNEG;
}

// ---------------------------------------------------------------------------
// Kernel 2: weight prep — transpose to Wt[n][k], bf16, Wq scaled by SCALE2F.
// wt holds 4 matrices: z = 0..3 -> Wq,Wk,Wv,Wo. grid (4,4,4), 64x64 tiles.
// ---------------------------------------------------------------------------
__global__ __launch_bounds__(256) void wprep_kernel(
    const float* __restrict__ Wq, const float* __restrict__ Wk,
    const float* __restrict__ Wv, const float* __restrict__ Wo,
    ushort* __restrict__ wt)
{
    int z = blockIdx.z;
    const float* W = (z == 0) ? Wq : (z == 1) ? Wk : (z == 2) ? Wv : Wo;
    float scale = (z == 0) ? SCALE2F : 1.0f;
    ushort* out = wt + (size_t)z * DD * DD;
    int r0 = blockIdx.x * 64, c0 = blockIdx.y * 64;
    int tid = threadIdx.x;
    __shared__ float t[64][65];
    #pragma unroll
    for (int i = 0; i < 4; ++i) {
        int s  = tid + i * 256;
        int row = s >> 4, c4 = (s & 15) * 4;
        float4 v = *(const float4*)(W + (size_t)(r0 + row) * DD + c0 + c4);
        t[row][c4] = v.x; t[row][c4 + 1] = v.y; t[row][c4 + 2] = v.z; t[row][c4 + 3] = v.w;
    }
    __syncthreads();
    int nl = tid >> 2, ks = (tid & 3) * 16;
    ushort buf[16];
    #pragma unroll
    for (int j = 0; j < 16; ++j) buf[j] = f2bf(t[ks + j][nl] * scale);
    *(uint4*)(out + (size_t)(c0 + nl) * DD + r0 + ks)     = *(uint4*)&buf[0];
    *(uint4*)(out + (size_t)(c0 + nl) * DD + r0 + ks + 8) = *(uint4*)&buf[8];
}

// ---------------------------------------------------------------------------
// Kernel 3/5: bf16 MFMA GEMM  C[M,256] = A[M,256] @ W + b, no LDS:
// direct 16B fragment loads (A row-major, Wt n-major). 128x64 block, 4 waves.
// qkv=1: z=0,1 -> bf16 [B,H,K,32] (q,k); z=2 -> bf16 V^T [B,H,32,K]
// qkv=0: fp32 row-major (out projection, uses wt slot 3)
// ---------------------------------------------------------------------------
__global__ __launch_bounds__(256) void mfma_gemm_kernel(
    const ushort* __restrict__ A, const ushort* __restrict__ wt,
    const float* __restrict__ b0, const float* __restrict__ b1,
    const float* __restrict__ b2,
    void* __restrict__ o0, void* __restrict__ o1, void* __restrict__ o2,
    int qkv)
{
    int zz = qkv ? blockIdx.z : 3;
    const ushort* Wt = wt + (size_t)zz * DD * DD;
    const float* bp = qkv ? ((blockIdx.z == 0) ? b0 : (blockIdx.z == 1) ? b1 : b2) : b0;
    const int mode = qkv ? ((blockIdx.z == 2) ? 1 : 0) : 2;
    const float bsc = (qkv && blockIdx.z == 0) ? SCALE2F : 1.0f;

    int m0 = blockIdx.x * 128, n0 = blockIdx.y * 64;
    int tid = threadIdx.x;
    int w = tid >> 6, l = tid & 63, lg = l >> 4, ll = l & 15;
    int mrow = m0 + w * 32;

    f32x4 acc[2][4];
    #pragma unroll
    for (int mt = 0; mt < 2; ++mt)
        #pragma unroll
        for (int nt = 0; nt < 4; ++nt) acc[mt][nt] = (f32x4){0.f, 0.f, 0.f, 0.f};

    const ushort* Ab = A + (size_t)mrow * DD;
    #pragma unroll
    for (int kc = 0; kc < 8; ++kc) {
        bf16x8 af0 = *(const bf16x8*)(Ab + (size_t)ll * DD + kc * 32 + lg * 8);
        bf16x8 af1 = *(const bf16x8*)(Ab + (size_t)(16 + ll) * DD + kc * 32 + lg * 8);
        bf16x8 bfr[4];
        #pragma unroll
        for (int nt = 0; nt < 4; ++nt)
            bfr[nt] = *(const bf16x8*)(Wt + (size_t)(n0 + nt * 16 + ll) * DD + kc * 32 + lg * 8);
        #pragma unroll
        for (int nt = 0; nt < 4; ++nt) {
            acc[0][nt] = __builtin_amdgcn_mfma_f32_16x16x32_bf16(af0, bfr[nt], acc[0][nt], 0, 0, 0);
            acc[1][nt] = __builtin_amdgcn_mfma_f32_16x16x32_bf16(af1, bfr[nt], acc[1][nt], 0, 0, 0);
        }
    }

    float bias[4];
    #pragma unroll
    for (int nt = 0; nt < 4; ++nt) bias[nt] = bp[n0 + nt * 16 + ll] * bsc;

    if (mode == 0) {            // q / k : bf16 [B,H,K,32], scalar b16 stores
        ushort* op = (ushort*)((blockIdx.z == 0) ? o0 : o1);
        #pragma unroll
        for (int mt = 0; mt < 2; ++mt)
            #pragma unroll
            for (int nt = 0; nt < 4; ++nt) {
                int n = n0 + nt * 16 + ll, h = n >> 5, dI = n & 31;
                #pragma unroll
                for (int r = 0; r < 4; ++r) {
                    int tok = mrow + mt * 16 + lg * 4 + r;
                    op[((((size_t)(tok >> 11) * HH + h) * KK) + (tok & 2047)) * HD + dI] =
                        f2bf(acc[mt][nt][r] + bias[nt]);
                }
            }
    } else if (mode == 1) {     // V^T [B,H,32,K]: 4 consecutive toks -> b64
        ushort* op = (ushort*)o2;
        #pragma unroll
        for (int mt = 0; mt < 2; ++mt)
            #pragma unroll
            for (int nt = 0; nt < 4; ++nt) {
                int n = n0 + nt * 16 + ll, h = n >> 5, dI = n & 31;
                int tokb = mrow + mt * 16 + lg * 4;
                ushort u[4];
                #pragma unroll
                for (int r = 0; r < 4; ++r) u[r] = f2bf(acc[mt][nt][r] + bias[nt]);
                *(uint2*)(op + (((size_t)(tokb >> 11) * HH + h) * HD + dI) * KK + (tokb & 2047)) =
                    *(uint2*)u;
            }
    } else {                    // fp32 out projection
        float* op = (float*)o0;
        #pragma unroll
        for (int mt = 0; mt < 2; ++mt)
            #pragma unroll
            for (int nt = 0; nt < 4; ++nt)
                #pragma unroll
                for (int r = 0; r < 4; ++r)
                    op[(size_t)(mrow + mt * 16 + lg * 4 + r) * DD + n0 + nt * 16 + ll] =
                        acc[mt][nt][r] + bias[nt];
    }
}

// ---------------------------------------------------------------------------
// Kernel 4: masked flash attention, swapped-operand MFMA (S^T = K Q^T).
// Grid (K/64, H, B), 256 thr = 4 waves; wave owns 16 q rows (lane ll = q).
// Scores in log2 domain (scale folded into Wq). Mask = fmaf(qcf, mbias_k, s).
// In-lane key-max/sum trees + 2 shfl_xor; deferred rescale (THR=8).
// P -> swizzled LDS (b64 writes) -> b128 A-fragments; V pre-transposed.
// Output: bf16 ao [B,K,256].
// ---------------------------------------------------------------------------
__global__ __launch_bounds__(256, 4) void attn_mfma_kernel(
    const ushort* __restrict__ qb, const ushort* __restrict__ kb,
    const ushort* __restrict__ vt, const int* __restrict__ is_ctx,
    const float* __restrict__ mbias, ushort* __restrict__ ao)
{
    const int b  = blockIdx.z;
    const int h  = blockIdx.y;
    const int bh = b * HH + h;
    const int tid = threadIdx.x;
    const int w  = tid >> 6;
    const int l  = tid & 63;
    const int lg = l >> 4;
    const int ll = l & 15;
    const int q0 = blockIdx.x * 64 + w * 16;

    __shared__ ushort Pl[4][16][64];
    char* Pw = (char*)&Pl[w][0][0];
    const int sw = (ll & 7) << 4;                 // XOR swizzle for this lane's P row

    // Q fragment (B operand): lane = q col (ll), dims lg*8..+7
    bf16x8 qf = *(const bf16x8*)(qb + ((size_t)bh * KK + q0 + ll) * HD + lg * 8);
    const float qcf = (is_ctx[b * KK + q0 + ll] != 0) ? 1.0f : 0.0f;

    float m = -INFINITY, lacc = 0.0f;
    f32x4 acc[2];
    acc[0] = (f32x4){0.f, 0.f, 0.f, 0.f};
    acc[1] = (f32x4){0.f, 0.f, 0.f, 0.f};

    const ushort* kbase = kb + (size_t)bh * KK * HD;
    const ushort* vbase = vt + (size_t)bh * HD * KK;
    const float*  mbb   = mbias + (size_t)b * KK;
    const f32x4 zero = {0.f, 0.f, 0.f, 0.f};

    for (int kt0 = 0; kt0 < KK; kt0 += 64) {
        // S^T = K Q^T : row = key (quad), col = q (lane)
        f32x4 st[4];
        float4 mb[4];
        #pragma unroll
        for (int kt = 0; kt < 4; ++kt) {
            bf16x8 kf = *(const bf16x8*)(kbase + (size_t)(kt0 + kt * 16 + ll) * HD + lg * 8);
            mb[kt] = *(const float4*)(mbb + kt0 + kt * 16 + lg * 4);
            st[kt] = __builtin_amdgcn_mfma_f32_16x16x32_bf16(kf, qf, zero, 0, 0, 0);
        }
        // masked scores (log2 domain): s = qcf * bias_k + s
        float s[16];
        #pragma unroll
        for (int kt = 0; kt < 4; ++kt) {
            s[kt * 4 + 0] = fmaf(qcf, mb[kt].x, st[kt][0]);
            s[kt * 4 + 1] = fmaf(qcf, mb[kt].y, st[kt][1]);
            s[kt * 4 + 2] = fmaf(qcf, mb[kt].z, st[kt][2]);
            s[kt * 4 + 3] = fmaf(qcf, mb[kt].w, st[kt][3]);
        }
        // row max: in-lane tree + cross-group
        float t0 = fmaxf(fmaxf(s[0], s[1]),  fmaxf(s[2], s[3]));
        float t1 = fmaxf(fmaxf(s[4], s[5]),  fmaxf(s[6], s[7]));
        float t2 = fmaxf(fmaxf(s[8], s[9]),  fmaxf(s[10], s[11]));
        float t3 = fmaxf(fmaxf(s[12], s[13]), fmaxf(s[14], s[15]));
        float tmax = fmaxf(fmaxf(t0, t1), fmaxf(t2, t3));
        tmax = fmaxf(tmax, __shfl_xor(tmax, 16));
        tmax = fmaxf(tmax, __shfl_xor(tmax, 32));

        if (__any(tmax > m + 8.0f)) {             // deferred rescale
            float mnew = fmaxf(fmaxf(m, tmax), -1e37f);
            float corr = exp2f(m - mnew);
            m = mnew;
            lacc *= corr;
            #pragma unroll
            for (int r = 0; r < 4; ++r) {
                float cr = __shfl(corr, lg * 4 + r);
                acc[0][r] *= cr;
                acc[1][r] *= cr;
            }
        }
        float msafe = fmaxf(m, -1e37f);

        float ps = 0.0f;
        #pragma unroll
        for (int kt = 0; kt < 4; ++kt) {
            float p0 = exp2f(s[kt * 4 + 0] - msafe);
            float p1 = exp2f(s[kt * 4 + 1] - msafe);
            float p2 = exp2f(s[kt * 4 + 2] - msafe);
            float p3 = exp2f(s[kt * 4 + 3] - msafe);
            ps += (p0 + p1) + (p2 + p3);
            uint2 uu;
            uu.x = pkbf(p0, p1);
            uu.y = pkbf(p2, p3);
            *(uint2*)(Pw + ll * 128 + ((kt * 32 + lg * 8) ^ sw)) = uu;
        }
        ps += __shfl_xor(ps, 16);
        ps += __shfl_xor(ps, 32);
        lacc += ps;

        // O += P V : A = P (LDS), B = V^T rows (contiguous)
        #pragma unroll
        for (int ks = 0; ks < 2; ++ks) {
            bf16x8 pf = *(const bf16x8*)(Pw + ll * 128 + ((ks * 64 + lg * 16) ^ sw));
            #pragma unroll
            for (int dt = 0; dt < 2; ++dt) {
                bf16x8 vf = *(const bf16x8*)(vbase + (size_t)(dt * 16 + ll) * KK + kt0 + ks * 32 + lg * 8);
                acc[dt] = __builtin_amdgcn_mfma_f32_16x16x32_bf16(pf, vf, acc[dt], 0, 0, 0);
            }
        }
    }

    // epilogue: O row = lg*4+r, col = ll; l lives at lane ll=q -> bpermute
    float inv = 1.0f / lacc;
    #pragma unroll
    for (int r = 0; r < 4; ++r) {
        float iv = __shfl(inv, lg * 4 + r);
        int q = q0 + lg * 4 + r;
        ushort* orow = ao + ((size_t)b * KK + q) * DD + h * HD;
        orow[ll]      = f2bf(acc[0][r] * iv);
        orow[16 + ll] = f2bf(acc[1][r] * iv);
    }
}

// ---------------------------------------------------------------------------
extern "C" void kernel_launch(void* const* d_in, const int* in_sizes, int n_in,
                              void* d_out, int out_size, void* d_ws, size_t ws_size,
                              hipStream_t stream)
{
    const float* x        = (const float*)d_in[0];
    const int*   coords   = (const int*)  d_in[1];
    const int*   is_ctx   = (const int*)  d_in[2];
    const int*   img_sz   = (const int*)  d_in[3];
    const float* Wq       = (const float*)d_in[4];
    const float* bq       = (const float*)d_in[5];
    const float* Wk       = (const float*)d_in[6];
    const float* bk       = (const float*)d_in[7];
    const float* Wv       = (const float*)d_in[8];
    const float* bv       = (const float*)d_in[9];
    const float* Wo       = (const float*)d_in[10];
    const float* bo       = (const float*)d_in[11];
    const float* rope     = (const float*)d_in[12];

    int max_pos = in_sizes[12] / (QUARTER * 2);   // 224

    const size_t NTOK = (size_t)BB * KK;          // 8192
    const size_t NELT = NTOK * DD;                // 2,097,152 elements

    char* ws = (char*)d_ws;
    ushort* xr16  = (ushort*)(ws);                     // 4 MB
    ushort* qbf   = (ushort*)(ws + NELT * 2);          // 4 MB
    ushort* kbf   = (ushort*)(ws + NELT * 4);          // 4 MB
    ushort* vtbf  = (ushort*)(ws + NELT * 6);          // 4 MB
    ushort* ao16  = (ushort*)(ws + NELT * 8);          // 4 MB
    ushort* wt    = (ushort*)(ws + NELT * 10);         // 512 KB (4 x 256x256)
    float*  mbias = (float*) (ws + NELT * 10 + 4 * DD * DD * 2);  // 32 KB
    float* outp = (float*)d_out;

    // 1) RoPE -> bf16 xr + mask bias array
    {
        int total = BB * KK * HALF;
        rope_kernel<<<(total + 255) / 256, 256, 0, stream>>>(
            x, coords, rope, img_sz, is_ctx, max_pos, xr16, mbias);
    }
    // 2) weight prep: transpose + bf16 (+ SCALE2F fold into Wq)
    wprep_kernel<<<dim3(4, 4, 4), 256, 0, stream>>>(Wq, Wk, Wv, Wo, wt);
    // 3) QKV projections (bf16 MFMA)
    mfma_gemm_kernel<<<dim3(NTOK / 128, DD / 64, 3), 256, 0, stream>>>(
        xr16, wt, bq, bk, bv, qbf, kbf, vtbf, 1);
    // 4) attention
    attn_mfma_kernel<<<dim3(KK / 64, HH, BB), 256, 0, stream>>>(
        qbf, kbf, vtbf, is_ctx, mbias, ao16);
    // 5) output projection (bf16 MFMA, fp32 out)
    mfma_gemm_kernel<<<dim3(NTOK / 128, DD / 64, 1), 256, 0, stream>>>(
        ao16, wt, bo, bo, bo, outp, outp, outp, 0);
}